// Round 10
// baseline (4160.179 us; speedup 1.0000x reference)
//
#include <hip/hip_runtime.h>

typedef unsigned short u16;
typedef short s16x8 __attribute__((ext_vector_type(8)));
typedef short s16x4 __attribute__((ext_vector_type(4)));
typedef float f32x4 __attribute__((ext_vector_type(4)));

#define SEQ   2048
#define BATCH 2
#define NHEAD 16

__device__ __forceinline__ float b2f(u16 u) {
    unsigned x = ((unsigned)u) << 16;
    return __builtin_bit_cast(float, x);
}
__device__ __forceinline__ u16 f2b(float f) {
    unsigned x = __builtin_bit_cast(unsigned, f);
    unsigned r = (x + 0x7fffu + ((x >> 16) & 1u)) >> 16;
    return (u16)r;
}
__device__ __forceinline__ void b2x2(unsigned u, float& a, float& b) {
    a = __builtin_bit_cast(float, u << 16);
    b = __builtin_bit_cast(float, u & 0xffff0000u);
}

// ---------------------------------------------------------------------------
// MFMA GEMM: C[M,N] = A[M,K] @ W[N,K]^T + bias[N]
// A: f32 (A_F32=1, lda elements) or bf16 (A_F32=0, lda elements). W,bias: f32.
// C: bf16 (OUT_BF16=1) or f32. Tile 128x64, BK=64, 4 waves (2x2).
// Fragment layout validated bit-identical vs scalar reference GEMM (R2 vs R3).
// ---------------------------------------------------------------------------
template <int A_F32, int OUT_BF16>
__global__ __launch_bounds__(256) void gemm_bias_k(
    const void* __restrict__ Av, const float* __restrict__ W,
    const float* __restrict__ bias, void* __restrict__ Cout,
    int M, int N, int K, int lda)
{
    __shared__ short lsA[128][72];
    __shared__ short lsW[64][72];
    const int tid  = threadIdx.x;
    const int lane = tid & 63;
    const int wid  = tid >> 6;
    const int wm   = wid >> 1, wn = wid & 1;
    const int row0 = blockIdx.y * 128;
    const int col0 = blockIdx.x * 64;

    f32x4 acc[4][2];
#pragma unroll
    for (int i = 0; i < 4; i++)
#pragma unroll
        for (int j = 0; j < 2; j++) acc[i][j] = (f32x4){0.f, 0.f, 0.f, 0.f};

    for (int kt = 0; kt < K; kt += 64) {
        if (A_F32) {
            const float* Af = (const float*)Av;
#pragma unroll
            for (int t = 0; t < 8; t++) {
                int idx = tid + t * 256;
                int r = idx >> 4, c4 = idx & 15;
                float4 v = *(const float4*)(Af + (size_t)(row0 + r) * lda + kt + c4 * 4);
                s16x4 o = { (short)f2b(v.x), (short)f2b(v.y), (short)f2b(v.z), (short)f2b(v.w) };
                *(s16x4*)&lsA[r][c4 * 4] = o;
            }
        } else {
            const u16* Ab = (const u16*)Av;
#pragma unroll
            for (int t = 0; t < 4; t++) {
                int idx = tid + t * 256;
                int r = idx >> 3, c = idx & 7;
                s16x8 v = *(const s16x8*)(Ab + (size_t)(row0 + r) * lda + kt + c * 8);
                *(s16x4*)&lsA[r][c * 8]     = __builtin_shufflevector(v, v, 0, 1, 2, 3);
                *(s16x4*)&lsA[r][c * 8 + 4] = __builtin_shufflevector(v, v, 4, 5, 6, 7);
            }
        }
#pragma unroll
        for (int t = 0; t < 4; t++) {
            int idx = tid + t * 256;
            int r = idx >> 4, c4 = idx & 15;
            float4 v = *(const float4*)(W + (size_t)(col0 + r) * K + kt + c4 * 4);
            s16x4 o = { (short)f2b(v.x), (short)f2b(v.y), (short)f2b(v.z), (short)f2b(v.w) };
            *(s16x4*)&lsW[r][c4 * 4] = o;
        }
        __syncthreads();
#pragma unroll
        for (int ks = 0; ks < 2; ks++) {
            const int kb = ks * 32 + ((lane >> 4) << 2);
            s16x8 af[4], wf[2];
            const int ra = wm * 64 + (lane & 15);
#pragma unroll
            for (int mf = 0; mf < 4; mf++) {
                s16x4 lo = *(const s16x4*)&lsA[ra + mf * 16][kb];
                s16x4 hi = *(const s16x4*)&lsA[ra + mf * 16][kb + 16];
                af[mf] = __builtin_shufflevector(lo, hi, 0, 1, 2, 3, 4, 5, 6, 7);
            }
            const int rw = wn * 32 + (lane & 15);
#pragma unroll
            for (int nf = 0; nf < 2; nf++) {
                s16x4 lo = *(const s16x4*)&lsW[rw + nf * 16][kb];
                s16x4 hi = *(const s16x4*)&lsW[rw + nf * 16][kb + 16];
                wf[nf] = __builtin_shufflevector(lo, hi, 0, 1, 2, 3, 4, 5, 6, 7);
            }
#pragma unroll
            for (int mf = 0; mf < 4; mf++)
#pragma unroll
                for (int nf = 0; nf < 2; nf++)
                    acc[mf][nf] = __builtin_amdgcn_mfma_f32_16x16x32_bf16(
                        af[mf], wf[nf], acc[mf][nf], 0, 0, 0);
        }
        __syncthreads();
    }

    const int rb = row0 + wm * 64 + ((lane >> 4) << 2);
    const int cb = col0 + wn * 32 + (lane & 15);
#pragma unroll
    for (int nf = 0; nf < 2; nf++) {
        const int col = cb + nf * 16;
        const float bv = bias[col];
#pragma unroll
        for (int mf = 0; mf < 4; mf++) {
#pragma unroll
            for (int r = 0; r < 4; r++) {
                const int row = rb + mf * 16 + r;
                float v = acc[mf][nf][r] + bv;
                if (OUT_BF16) ((u16*)Cout)[(size_t)row * N + col] = f2b(v);
                else          ((float*)Cout)[(size_t)row * N + col] = v;
            }
        }
    }
}

// ---------------------------------------------------------------------------
// In-place RMSNorm on bf16 rows
// ---------------------------------------------------------------------------
__global__ __launch_bounds__(256) void rmsnorm_ip_k(
    u16* __restrict__ buf, const float* __restrict__ w, int cols, int stride)
{
    const int row = blockIdx.x;
    u16* xr = buf + (size_t)row * stride;
    float ss = 0.f;
    for (int c = threadIdx.x; c < cols; c += 256) { float v = b2f(xr[c]); ss += v * v; }
#pragma unroll
    for (int off = 32; off; off >>= 1) ss += __shfl_xor(ss, off);
    __shared__ float red[4];
    if ((threadIdx.x & 63) == 0) red[threadIdx.x >> 6] = ss;
    __syncthreads();
    const float tot = red[0] + red[1] + red[2] + red[3];
    const float inv = rsqrtf(tot / (float)cols + 1.1920929e-7f);
    for (int c = threadIdx.x; c < cols; c += 256)
        xr[c] = f2b(b2f(xr[c]) * inv * w[c]);
}

// ---------------------------------------------------------------------------
// RoPE kernels
// ---------------------------------------------------------------------------
__global__ __launch_bounds__(256) void rope_q_k(
    u16* __restrict__ qb, const float* __restrict__ fc, const float* __restrict__ fs)
{
    const int idx = blockIdx.x * 256 + threadIdx.x;
    const int i = idx & 31;
    const int h = (idx >> 5) & 15;
    const int row = idx >> 9;
    const int s = row & (SEQ - 1);
    ushort2* p = (ushort2*)(qb + (size_t)row * 3072 + h * 192 + 128) + i;
    ushort2 v = *p;
    const float xr = b2f(v.x), xi = b2f(v.y);
    const float c = fc[s * 32 + i], sn = fs[s * 32 + i];
    ushort2 o;
    o.x = f2b(xr * c - xi * sn);
    o.y = f2b(xr * sn + xi * c);
    *p = o;
}

__global__ __launch_bounds__(256) void rope_k_k(
    const u16* __restrict__ kvb, const float* __restrict__ fc,
    const float* __restrict__ fs, u16* __restrict__ krope)
{
    const int idx = blockIdx.x * 256 + threadIdx.x;
    const int i = idx & 31;
    const int row = idx >> 5;
    const int s = row & (SEQ - 1);
    const u16* src = kvb + (size_t)row * 576 + 512 + 2 * i;
    const float xr = b2f(src[0]), xi = b2f(src[1]);
    const float c = fc[s * 32 + i], sn = fs[s * 32 + i];
    ushort2 o;
    o.x = f2b(xr * c - xi * sn);
    o.y = f2b(xr * sn + xi * c);
    *((ushort2*)(krope + (size_t)row * 64) + i) = o;
}

// ---------------------------------------------------------------------------
// Flash attention, 1 wave per (b,h,q) row
// ---------------------------------------------------------------------------
__device__ __forceinline__ float dot8(const uint4 v, const float* qp) {
    float a0, a1, acc = 0.f;
    b2x2(v.x, a0, a1); acc += qp[0] * a0 + qp[1] * a1;
    b2x2(v.y, a0, a1); acc += qp[2] * a0 + qp[3] * a1;
    b2x2(v.z, a0, a1); acc += qp[4] * a0 + qp[5] * a1;
    b2x2(v.w, a0, a1); acc += qp[6] * a0 + qp[7] * a1;
    return acc;
}

__global__ __launch_bounds__(64) void attn_k(
    const u16* __restrict__ Q, const u16* __restrict__ KNV,
    const u16* __restrict__ KR, u16* __restrict__ O)
{
    __shared__ float qs[192];
    __shared__ float pl[64];
    const int lane = threadIdx.x;
    const int w = blockIdx.x;
    const int q = w & (SEQ - 1);
    const int bh = w >> 11;
    const int h = bh & (NHEAD - 1);
    const int b = bh >> 4;
    const size_t rowq = (size_t)b * SEQ + q;

    for (int t = lane; t < 192; t += 64)
        qs[t] = b2f(Q[rowq * 3072 + h * 192 + t]);
    __syncthreads();

    float m = -1e30f, l = 0.f, o0 = 0.f, o1 = 0.f;
    const float scale = 0.07216878364870323f;  // 192^-0.5

    for (int kk = 0; kk <= q; kk += 64) {
        const int k = kk + lane;
        float s = 0.f;
        {
            const uint4* kp = (const uint4*)(KNV + ((size_t)b * SEQ + k) * 4096 + h * 256);
#pragma unroll
            for (int d4 = 0; d4 < 16; d4++) s += dot8(kp[d4], &qs[d4 * 8]);
            const uint4* rp = (const uint4*)(KR + ((size_t)b * SEQ + k) * 64);
#pragma unroll
            for (int d4 = 0; d4 < 8; d4++) s += dot8(rp[d4], &qs[128 + d4 * 8]);
        }
        s *= scale;
        const bool valid = (k <= q);
        const float sv = valid ? s : -1e30f;
        float tm = sv;
#pragma unroll
        for (int off = 32; off; off >>= 1) tm = fmaxf(tm, __shfl_xor(tm, off));
        const float nm = fmaxf(m, tm);
        const float p = valid ? __expf(sv - nm) : 0.f;
        float ps = p;
#pragma unroll
        for (int off = 32; off; off >>= 1) ps += __shfl_xor(ps, off);
        const float corr = __expf(m - nm);
        l = l * corr + ps;
        o0 *= corr; o1 *= corr;
        pl[lane] = p;
        __syncthreads();
        const int jc = min(64, q - kk + 1);
        const int jcr = (jc + 3) & ~3;
        const u16* vb = KNV + ((size_t)b * SEQ + kk) * 4096 + h * 256 + 128 + 2 * lane;
        for (int j4 = 0; j4 < jcr; j4 += 4) {
            const f32x4 pv = *(const f32x4*)&pl[j4];
#pragma unroll
            for (int e = 0; e < 4; e++) {
                const unsigned uv = *(const unsigned*)(vb + (size_t)(j4 + e) * 4096);
                float v0, v1; b2x2(uv, v0, v1);
                o0 += pv[e] * v0;
                o1 += pv[e] * v1;
            }
        }
        m = nm;
        __syncthreads();
    }
    const float invl = 1.f / l;
    u16* op = O + rowq * 2048 + h * 128 + 2 * lane;
    op[0] = f2b(o0 * invl);
    op[1] = f2b(o1 * invl);
}

// ---------------------------------------------------------------------------
extern "C" void kernel_launch(void* const* d_in, const int* in_sizes, int n_in,
                              void* d_out, int out_size, void* d_ws, size_t ws_size,
                              hipStream_t stream)
{
    const float* x    = (const float*)d_in[0];
    const float* fc   = (const float*)d_in[1];
    const float* fs   = (const float*)d_in[2];
    const float* Wqd  = (const float*)d_in[3];
    const float* bqd  = (const float*)d_in[4];
    const float* qnw  = (const float*)d_in[5];
    const float* Wqu  = (const float*)d_in[6];
    const float* bqu  = (const float*)d_in[7];
    const float* Wkvd = (const float*)d_in[8];
    const float* bkvd = (const float*)d_in[9];
    const float* kvnw = (const float*)d_in[10];
    const float* Wkvu = (const float*)d_in[11];
    const float* bkvu = (const float*)d_in[12];
    const float* Wo   = (const float*)d_in[13];
    const float* bo   = (const float*)d_in[14];

    char* ws = (char*)d_ws;
    u16* kvb    = (u16*)(ws);                 // [4096][576]  bf16
    u16* qlat   = (u16*)(ws + 4718592);       // [4096][1536] bf16
    u16* qbuf   = (u16*)(ws + 17301504);      // [4096][3072] bf16
    u16* krope  = (u16*)(ws + 42467328);      // [4096][64]   bf16
    u16* knv    = (u16*)(ws + 42991616);      // [4096][4096] bf16 (ends 76546048)
    u16* attn_o = (u16*)(ws);                 // [4096][2048] bf16, reuses kvb+qlat

    const int M = BATCH * SEQ;  // 4096

    // 1) q down-proj -> bf16 qlat
    gemm_bias_k<1, 1><<<dim3(24, 32), 256, 0, stream>>>(x, Wqd, bqd, qlat, M, 1536, 2048, 2048);
    // 2) kv down-proj -> bf16 kvb
    gemm_bias_k<1, 1><<<dim3(9, 32), 256, 0, stream>>>(x, Wkvd, bkvd, kvb, M, 576, 2048, 2048);
    // 3) rmsnorm in place
    rmsnorm_ip_k<<<M, 256, 0, stream>>>(qlat, qnw, 1536, 1536);
    rmsnorm_ip_k<<<M, 256, 0, stream>>>(kvb, kvnw, 512, 576);
    // 4) rope on shared k -> krope
    rope_k_k<<<(M * 32) / 256, 256, 0, stream>>>(kvb, fc, fs, krope);
    // 5) q up-proj -> qbuf
    gemm_bias_k<0, 1><<<dim3(48, 32), 256, 0, stream>>>(qlat, Wqu, bqu, qbuf, M, 3072, 1536, 1536);
    // 6) rope on q (in place)
    rope_q_k<<<(M * 16 * 32) / 256, 256, 0, stream>>>(qbuf, fc, fs);
    // 7) kv up-proj -> knv (A = kvb, lda=576, K=512)
    gemm_bias_k<0, 1><<<dim3(64, 32), 256, 0, stream>>>(kvb, Wkvu, bkvu, knv, M, 4096, 512, 576);
    // 8) causal attention -> attn_o
    attn_k<<<BATCH * NHEAD * SEQ, 64, 0, stream>>>(qbuf, knv, krope, attn_o);
    // 9) output projection -> d_out as FLOAT32
    gemm_bias_k<0, 0><<<dim3(32, 32), 256, 0, stream>>>(attn_o, Wo, bo, (float*)d_out, M, 2048, 2048, 2048);
}

// Round 11
// 596.370 us; speedup vs baseline: 6.9758x; 6.9758x over previous
//
#include <hip/hip_runtime.h>

typedef unsigned short u16;
typedef short s16x8 __attribute__((ext_vector_type(8)));
typedef short s16x4 __attribute__((ext_vector_type(4)));
typedef float f32x4 __attribute__((ext_vector_type(4)));

#define SEQ   2048
#define BATCH 2
#define NHEAD 16

__device__ __forceinline__ float b2f(u16 u) {
    unsigned x = ((unsigned)u) << 16;
    return __builtin_bit_cast(float, x);
}
__device__ __forceinline__ u16 f2b(float f) {
    unsigned x = __builtin_bit_cast(unsigned, f);
    unsigned r = (x + 0x7fffu + ((x >> 16) & 1u)) >> 16;
    return (u16)r;
}
__device__ __forceinline__ s16x8 comb(s16x4 lo, s16x4 hi) {
    return __builtin_shufflevector(lo, hi, 0, 1, 2, 3, 4, 5, 6, 7);
}

// ---------------------------------------------------------------------------
// MFMA GEMM: C[M,N] = A[M,K] @ W[N,K]^T + bias[N]   (validated R2 vs R3)
// ---------------------------------------------------------------------------
template <int A_F32, int OUT_BF16>
__global__ __launch_bounds__(256) void gemm_bias_k(
    const void* __restrict__ Av, const float* __restrict__ W,
    const float* __restrict__ bias, void* __restrict__ Cout,
    int M, int N, int K, int lda)
{
    __shared__ short lsA[128][72];
    __shared__ short lsW[64][72];
    const int tid  = threadIdx.x;
    const int lane = tid & 63;
    const int wid  = tid >> 6;
    const int wm   = wid >> 1, wn = wid & 1;
    const int row0 = blockIdx.y * 128;
    const int col0 = blockIdx.x * 64;

    f32x4 acc[4][2];
#pragma unroll
    for (int i = 0; i < 4; i++)
#pragma unroll
        for (int j = 0; j < 2; j++) acc[i][j] = (f32x4){0.f, 0.f, 0.f, 0.f};

    for (int kt = 0; kt < K; kt += 64) {
        if (A_F32) {
            const float* Af = (const float*)Av;
#pragma unroll
            for (int t = 0; t < 8; t++) {
                int idx = tid + t * 256;
                int r = idx >> 4, c4 = idx & 15;
                float4 v = *(const float4*)(Af + (size_t)(row0 + r) * lda + kt + c4 * 4);
                s16x4 o = { (short)f2b(v.x), (short)f2b(v.y), (short)f2b(v.z), (short)f2b(v.w) };
                *(s16x4*)&lsA[r][c4 * 4] = o;
            }
        } else {
            const u16* Ab = (const u16*)Av;
#pragma unroll
            for (int t = 0; t < 4; t++) {
                int idx = tid + t * 256;
                int r = idx >> 3, c = idx & 7;
                s16x8 v = *(const s16x8*)(Ab + (size_t)(row0 + r) * lda + kt + c * 8);
                *(s16x4*)&lsA[r][c * 8]     = __builtin_shufflevector(v, v, 0, 1, 2, 3);
                *(s16x4*)&lsA[r][c * 8 + 4] = __builtin_shufflevector(v, v, 4, 5, 6, 7);
            }
        }
#pragma unroll
        for (int t = 0; t < 4; t++) {
            int idx = tid + t * 256;
            int r = idx >> 4, c4 = idx & 15;
            float4 v = *(const float4*)(W + (size_t)(col0 + r) * K + kt + c4 * 4);
            s16x4 o = { (short)f2b(v.x), (short)f2b(v.y), (short)f2b(v.z), (short)f2b(v.w) };
            *(s16x4*)&lsW[r][c4 * 4] = o;
        }
        __syncthreads();
#pragma unroll
        for (int ks = 0; ks < 2; ks++) {
            const int kb = ks * 32 + ((lane >> 4) << 2);
            s16x8 af[4], wf[2];
            const int ra = wm * 64 + (lane & 15);
#pragma unroll
            for (int mf = 0; mf < 4; mf++)
                af[mf] = comb(*(const s16x4*)&lsA[ra + mf * 16][kb],
                              *(const s16x4*)&lsA[ra + mf * 16][kb + 16]);
            const int rw = wn * 32 + (lane & 15);
#pragma unroll
            for (int nf = 0; nf < 2; nf++)
                wf[nf] = comb(*(const s16x4*)&lsW[rw + nf * 16][kb],
                              *(const s16x4*)&lsW[rw + nf * 16][kb + 16]);
#pragma unroll
            for (int mf = 0; mf < 4; mf++)
#pragma unroll
                for (int nf = 0; nf < 2; nf++)
                    acc[mf][nf] = __builtin_amdgcn_mfma_f32_16x16x32_bf16(
                        af[mf], wf[nf], acc[mf][nf], 0, 0, 0);
        }
        __syncthreads();
    }

    const int rb = row0 + wm * 64 + ((lane >> 4) << 2);
    const int cb = col0 + wn * 32 + (lane & 15);
#pragma unroll
    for (int nf = 0; nf < 2; nf++) {
        const int col = cb + nf * 16;
        const float bv = bias[col];
#pragma unroll
        for (int mf = 0; mf < 4; mf++) {
#pragma unroll
            for (int r = 0; r < 4; r++) {
                const int row = rb + mf * 16 + r;
                float v = acc[mf][nf][r] + bv;
                if (OUT_BF16) ((u16*)Cout)[(size_t)row * N + col] = f2b(v);
                else          ((float*)Cout)[(size_t)row * N + col] = v;
            }
        }
    }
}

// ---------------------------------------------------------------------------
// In-place RMSNorm on bf16 rows
// ---------------------------------------------------------------------------
__global__ __launch_bounds__(256) void rmsnorm_ip_k(
    u16* __restrict__ buf, const float* __restrict__ w, int cols, int stride)
{
    const int row = blockIdx.x;
    u16* xr = buf + (size_t)row * stride;
    float ss = 0.f;
    for (int c = threadIdx.x; c < cols; c += 256) { float v = b2f(xr[c]); ss += v * v; }
#pragma unroll
    for (int off = 32; off; off >>= 1) ss += __shfl_xor(ss, off);
    __shared__ float red[4];
    if ((threadIdx.x & 63) == 0) red[threadIdx.x >> 6] = ss;
    __syncthreads();
    const float tot = red[0] + red[1] + red[2] + red[3];
    const float inv = rsqrtf(tot / (float)cols + 1.1920929e-7f);
    for (int c = threadIdx.x; c < cols; c += 256)
        xr[c] = f2b(b2f(xr[c]) * inv * w[c]);
}

// ---------------------------------------------------------------------------
// RoPE kernels
// ---------------------------------------------------------------------------
__global__ __launch_bounds__(256) void rope_q_k(
    u16* __restrict__ qb, const float* __restrict__ fc, const float* __restrict__ fs)
{
    const int idx = blockIdx.x * 256 + threadIdx.x;
    const int i = idx & 31;
    const int h = (idx >> 5) & 15;
    const int row = idx >> 9;
    const int s = row & (SEQ - 1);
    ushort2* p = (ushort2*)(qb + (size_t)row * 3072 + h * 192 + 128) + i;
    ushort2 v = *p;
    const float xr = b2f(v.x), xi = b2f(v.y);
    const float c = fc[s * 32 + i], sn = fs[s * 32 + i];
    ushort2 o;
    o.x = f2b(xr * c - xi * sn);
    o.y = f2b(xr * sn + xi * c);
    *p = o;
}

__global__ __launch_bounds__(256) void rope_k_k(
    const u16* __restrict__ kvb, const float* __restrict__ fc,
    const float* __restrict__ fs, u16* __restrict__ krope)
{
    const int idx = blockIdx.x * 256 + threadIdx.x;
    const int i = idx & 31;
    const int row = idx >> 5;
    const int s = row & (SEQ - 1);
    const u16* src = kvb + (size_t)row * 576 + 512 + 2 * i;
    const float xr = b2f(src[0]), xi = b2f(src[1]);
    const float c = fc[s * 32 + i], sn = fs[s * 32 + i];
    ushort2 o;
    o.x = f2b(xr * c - xi * sn);
    o.y = f2b(xr * sn + xi * c);
    *((ushort2*)(krope + (size_t)row * 64) + i) = o;
}

// ---------------------------------------------------------------------------
// MFMA flash attention.
// Block = (b, h, 64-row q-tile); 4 waves x 16 q-rows. K-tiles of 32 keys.
// Q bf16 [4096][3072] (rope applied); KNV [4096][4096] per head {K_nope,V};
// KR [4096][64]; O bf16 [4096][2048].
// ---------------------------------------------------------------------------
__global__ __launch_bounds__(256) void attn_k(
    const u16* __restrict__ Q, const u16* __restrict__ KNV,
    const u16* __restrict__ KR, u16* __restrict__ O)
{
    __shared__ u16 k_lds[32][200];    // 32 keys x 192 dims (pad 200)
    __shared__ u16 v_t[128][36];      // V transposed: [dim][key] (pad 36)
    __shared__ u16 p_lds[4][16][36];  // per-wave P: [qrow][key]

    const int tid  = threadIdx.x;
    const int lane = tid & 63;
    const int w    = tid >> 6;
    const int lr   = lane & 15;
    const int lq   = lane >> 4;

    const int bid = blockIdx.x;
    const int qt  = 31 - (bid >> 5);       // heavy tiles first
    const int bh  = bid & 31;
    const int h   = bh & 15;
    const int b   = bh >> 4;
    const int q0  = qt * 64;
    const int bS  = b * SEQ;

    // Q fragments in registers: 6 chunks of 32 dims
    s16x8 qf[6];
    {
        const u16* qp = Q + (size_t)(bS + q0 + w * 16 + lr) * 3072 + h * 192 + (lq << 2);
#pragma unroll
        for (int kc = 0; kc < 6; kc++)
            qf[kc] = comb(*(const s16x4*)(qp + kc * 32),
                          *(const s16x4*)(qp + kc * 32 + 16));
    }

    f32x4 o_acc[8];
#pragma unroll
    for (int d = 0; d < 8; d++) o_acc[d] = (f32x4){0.f, 0.f, 0.f, 0.f};
    float m[4] = { -1e30f, -1e30f, -1e30f, -1e30f };
    float l[4] = { 0.f, 0.f, 0.f, 0.f };
    const float scale = 0.07216878364870323f;  // 192^-0.5
    const int qmin_w = q0 + w * 16;            // smallest q-row of this wave

    for (int kt0 = 0; kt0 < q0 + 64; kt0 += 32) {
        __syncthreads();
        // ---- stage K (192) and V^T (128) for 32 keys -----------------------
        const size_t knv0 = (size_t)(bS + kt0) * 4096 + h * 256;
#pragma unroll
        for (int t = 0; t < 5; t++) {
            int idx = tid + t * 256;                 // 0..1279
            if (idx < 512) {                         // K_nope: 32x(128/8)
                int key = idx >> 4, c8 = (idx & 15) * 8;
                s16x8 v = *(const s16x8*)(KNV + knv0 + (size_t)key * 4096 + c8);
                *(s16x8*)&k_lds[key][c8] = v;
            } else if (idx < 768) {                  // K_rope: 32x(64/8)
                int j = idx - 512;
                int key = j >> 3, c8 = (j & 7) * 8;
                s16x8 v = *(const s16x8*)(KR + (size_t)(bS + kt0 + key) * 64 + c8);
                *(s16x8*)&k_lds[key][128 + c8] = v;
            } else {                                 // V transposed: 32x(128/8)
                int j = idx - 768;
                int key = j >> 4, d0 = (j & 15) * 8;
                s16x8 v = *(const s16x8*)(KNV + knv0 + (size_t)key * 4096 + 128 + d0);
#pragma unroll
                for (int e = 0; e < 8; e++) v_t[d0 + e][key] = (u16)v[e];
            }
        }
        __syncthreads();

        // ---- QK^T: 2 key-frags x 6 k-chunks --------------------------------
        f32x4 sa[2] = { (f32x4){0.f,0.f,0.f,0.f}, (f32x4){0.f,0.f,0.f,0.f} };
#pragma unroll
        for (int kc = 0; kc < 6; kc++) {
            const int kb = kc * 32 + (lq << 2);
#pragma unroll
            for (int f = 0; f < 2; f++) {
                s16x8 kf = comb(*(const s16x4*)&k_lds[f * 16 + lr][kb],
                                *(const s16x4*)&k_lds[f * 16 + lr][kb + 16]);
                sa[f] = __builtin_amdgcn_mfma_f32_16x16x32_bf16(qf[kc], kf, sa[f], 0, 0, 0);
            }
        }

        // ---- online softmax (per lane: 4 q-rows x 2 key-frags) -------------
        const bool need_mask = (kt0 + 31 > qmin_w);
        float p[2][4];
#pragma unroll
        for (int f = 0; f < 2; f++)
#pragma unroll
            for (int r = 0; r < 4; r++) {
                float s = sa[f][r] * scale;
                if (need_mask) {
                    int key = kt0 + f * 16 + lr;
                    int qr  = qmin_w + lq * 4 + r;
                    if (key > qr) s = -1e30f;
                }
                p[f][r] = s;
            }
        float nm[4], corr[4];
#pragma unroll
        for (int r = 0; r < 4; r++) {
            float tm = fmaxf(p[0][r], p[1][r]);
#pragma unroll
            for (int off = 8; off; off >>= 1) tm = fmaxf(tm, __shfl_xor(tm, off));
            nm[r] = fmaxf(m[r], tm);
            corr[r] = __expf(m[r] - nm[r]);
            m[r] = nm[r];
        }
#pragma unroll
        for (int f = 0; f < 2; f++)
#pragma unroll
            for (int r = 0; r < 4; r++)
                p[f][r] = __expf(p[f][r] - nm[r]);
#pragma unroll
        for (int r = 0; r < 4; r++) {
            float ps = p[0][r] + p[1][r];
#pragma unroll
            for (int off = 8; off; off >>= 1) ps += __shfl_xor(ps, off);
            l[r] = l[r] * corr[r] + ps;
        }
#pragma unroll
        for (int d = 0; d < 8; d++)
#pragma unroll
            for (int r = 0; r < 4; r++) o_acc[d][r] *= corr[r];

        // P -> LDS (per-wave buffer), bf16
#pragma unroll
        for (int f = 0; f < 2; f++)
#pragma unroll
            for (int r = 0; r < 4; r++)
                p_lds[w][lq * 4 + r][f * 16 + lr] = f2b(p[f][r]);
        asm volatile("s_waitcnt lgkmcnt(0)" ::: "memory");

        // ---- PV: A = P (k=32 keys), B = V^T frags --------------------------
        s16x8 pa = comb(*(const s16x4*)&p_lds[w][lr][lq << 2],
                        *(const s16x4*)&p_lds[w][lr][16 + (lq << 2)]);
#pragma unroll
        for (int d = 0; d < 8; d++) {
            s16x8 vf = comb(*(const s16x4*)&v_t[d * 16 + lr][lq << 2],
                            *(const s16x4*)&v_t[d * 16 + lr][16 + (lq << 2)]);
            o_acc[d] = __builtin_amdgcn_mfma_f32_16x16x32_bf16(pa, vf, o_acc[d], 0, 0, 0);
        }
    }

    // ---- epilogue: O /= l, store ------------------------------------------
    float invl[4];
#pragma unroll
    for (int r = 0; r < 4; r++) invl[r] = 1.f / l[r];
#pragma unroll
    for (int r = 0; r < 4; r++) {
        u16* op = O + (size_t)(bS + q0 + w * 16 + lq * 4 + r) * 2048 + h * 128 + lr;
#pragma unroll
        for (int d = 0; d < 8; d++)
            op[d * 16] = f2b(o_acc[d][r] * invl[r]);
    }
}

// ---------------------------------------------------------------------------
extern "C" void kernel_launch(void* const* d_in, const int* in_sizes, int n_in,
                              void* d_out, int out_size, void* d_ws, size_t ws_size,
                              hipStream_t stream)
{
    const float* x    = (const float*)d_in[0];
    const float* fc   = (const float*)d_in[1];
    const float* fs   = (const float*)d_in[2];
    const float* Wqd  = (const float*)d_in[3];
    const float* bqd  = (const float*)d_in[4];
    const float* qnw  = (const float*)d_in[5];
    const float* Wqu  = (const float*)d_in[6];
    const float* bqu  = (const float*)d_in[7];
    const float* Wkvd = (const float*)d_in[8];
    const float* bkvd = (const float*)d_in[9];
    const float* kvnw = (const float*)d_in[10];
    const float* Wkvu = (const float*)d_in[11];
    const float* bkvu = (const float*)d_in[12];
    const float* Wo   = (const float*)d_in[13];
    const float* bo   = (const float*)d_in[14];

    char* ws = (char*)d_ws;
    u16* kvb    = (u16*)(ws);                 // [4096][576]
    u16* qlat   = (u16*)(ws + 4718592);       // [4096][1536]
    u16* qbuf   = (u16*)(ws + 17301504);      // [4096][3072]
    u16* krope  = (u16*)(ws + 42467328);      // [4096][64]
    u16* knv    = (u16*)(ws + 42991616);      // [4096][4096]
    u16* attn_o = (u16*)(ws);                 // [4096][2048], reuses kvb+qlat

    const int M = BATCH * SEQ;  // 4096

    gemm_bias_k<1, 1><<<dim3(24, 32), 256, 0, stream>>>(x, Wqd, bqd, qlat, M, 1536, 2048, 2048);
    gemm_bias_k<1, 1><<<dim3(9, 32), 256, 0, stream>>>(x, Wkvd, bkvd, kvb, M, 576, 2048, 2048);
    rmsnorm_ip_k<<<M, 256, 0, stream>>>(qlat, qnw, 1536, 1536);
    rmsnorm_ip_k<<<M, 256, 0, stream>>>(kvb, kvnw, 512, 576);
    rope_k_k<<<(M * 32) / 256, 256, 0, stream>>>(kvb, fc, fs, krope);
    gemm_bias_k<0, 1><<<dim3(48, 32), 256, 0, stream>>>(qlat, Wqu, bqu, qbuf, M, 3072, 1536, 1536);
    rope_q_k<<<(M * 16 * 32) / 256, 256, 0, stream>>>(qbuf, fc, fs);
    gemm_bias_k<0, 1><<<dim3(64, 32), 256, 0, stream>>>(kvb, Wkvu, bkvu, knv, M, 4096, 512, 576);
    attn_k<<<BATCH * NHEAD * (SEQ / 64), 256, 0, stream>>>(qbuf, knv, krope, attn_o);
    gemm_bias_k<0, 0><<<dim3(32, 32), 256, 0, stream>>>(attn_o, Wo, bo, (float*)d_out, M, 2048, 2048, 2048);
}

// Round 12
// 518.567 us; speedup vs baseline: 8.0224x; 1.1500x over previous
//
#include <hip/hip_runtime.h>

typedef unsigned short u16;
typedef short s16x8 __attribute__((ext_vector_type(8)));
typedef short s16x4 __attribute__((ext_vector_type(4)));
typedef float f32x4 __attribute__((ext_vector_type(4)));

#define SEQ   2048
#define BATCH 2
#define NHEAD 16

__device__ __forceinline__ float b2f(u16 u) {
    unsigned x = ((unsigned)u) << 16;
    return __builtin_bit_cast(float, x);
}
__device__ __forceinline__ u16 f2b(float f) {
    unsigned x = __builtin_bit_cast(unsigned, f);
    unsigned r = (x + 0x7fffu + ((x >> 16) & 1u)) >> 16;
    return (u16)r;
}
__device__ __forceinline__ s16x8 comb(s16x4 lo, s16x4 hi) {
    return __builtin_shufflevector(lo, hi, 0, 1, 2, 3, 4, 5, 6, 7);
}
__device__ __forceinline__ void gload16(const void* g, void* l) {
    __builtin_amdgcn_global_load_lds(
        (const __attribute__((address_space(1))) void*)g,
        (__attribute__((address_space(3))) void*)l, 16, 0, 0);
}

// ---------------------------------------------------------------------------
// f32 -> bf16 convert (vectorized, grid-stride). n % 4 == 0.
// ---------------------------------------------------------------------------
__global__ __launch_bounds__(256) void cvt_bf16_k(
    const float* __restrict__ in, u16* __restrict__ out, int n4)
{
    int i = blockIdx.x * 256 + threadIdx.x;
    const int stride = gridDim.x * 256;
    for (; i < n4; i += stride) {
        float4 v = ((const float4*)in)[i];
        ushort4 o = { f2b(v.x), f2b(v.y), f2b(v.z), f2b(v.w) };
        ((ushort4*)out)[i] = o;
    }
}

// ---------------------------------------------------------------------------
// m97-style MFMA GEMM: C[M,N] = A[M,K](bf16) @ W[N,K](bf16)^T + bias[N](f32)
// 128x128 tile, BK=64, 4 waves (2x2), 4x4 16x16 frags/wave, global_load_lds.
// N-tiles may be partial (W row clamped, C col guarded). K%64==0, M%128==0.
// ---------------------------------------------------------------------------
template <int OUT_BF16>
__global__ __launch_bounds__(256) void gemm_bf_k(
    const u16* __restrict__ A, const u16* __restrict__ W,
    const float* __restrict__ bias, void* __restrict__ Cout,
    int M, int N, int K, int lda)
{
    __shared__ u16 lsA[128 * 64];
    __shared__ u16 lsB[128 * 64];
    const int tid  = threadIdx.x;
    const int lane = tid & 63;
    const int w    = tid >> 6;
    const int wm   = w >> 1, wn = w & 1;
    const int row0 = blockIdx.y * 128;
    const int col0 = blockIdx.x * 128;
    const int lr8  = lane >> 3;
    const int lc8  = (lane & 7) * 8;

    f32x4 acc[4][4];
#pragma unroll
    for (int i = 0; i < 4; i++)
#pragma unroll
        for (int j = 0; j < 4; j++) acc[i][j] = (f32x4){0.f, 0.f, 0.f, 0.f};

    for (int kt = 0; kt < K; kt += 64) {
#pragma unroll
        for (int t = 0; t < 4; t++) {
            const int r = w * 32 + t * 8;                     // wave-uniform
            gload16(A + (size_t)(row0 + r + lr8) * lda + kt + lc8, &lsA[r * 64]);
            int rw = col0 + r + lr8; if (rw >= N) rw = N - 1; // clamp partial tile
            gload16(W + (size_t)rw * K + kt + lc8, &lsB[r * 64]);
        }
        __syncthreads();
#pragma unroll
        for (int ks = 0; ks < 2; ks++) {
            const int ko = ks * 32 + (lane >> 4) * 8;         // k-contiguous frag
            s16x8 af[4], bfr[4];
#pragma unroll
            for (int i = 0; i < 4; i++) {
                af[i]  = *(const s16x8*)&lsA[(wm * 64 + i * 16 + (lane & 15)) * 64 + ko];
                bfr[i] = *(const s16x8*)&lsB[(wn * 64 + i * 16 + (lane & 15)) * 64 + ko];
            }
#pragma unroll
            for (int mf = 0; mf < 4; mf++)
#pragma unroll
                for (int nf = 0; nf < 4; nf++)
                    acc[mf][nf] = __builtin_amdgcn_mfma_f32_16x16x32_bf16(
                        af[mf], bfr[nf], acc[mf][nf], 0, 0, 0);
        }
        __syncthreads();
    }

    const int rb = row0 + wm * 64 + ((lane >> 4) << 2);
    const int cb = col0 + wn * 64 + (lane & 15);
#pragma unroll
    for (int nf = 0; nf < 4; nf++) {
        const int col = cb + nf * 16;
        if (col < N) {
            const float bv = bias[col];
#pragma unroll
            for (int mf = 0; mf < 4; mf++)
#pragma unroll
                for (int r = 0; r < 4; r++) {
                    const int row = rb + mf * 16 + r;
                    float v = acc[mf][nf][r] + bv;
                    if (OUT_BF16) ((u16*)Cout)[(size_t)row * N + col] = f2b(v);
                    else          ((float*)Cout)[(size_t)row * N + col] = v;
                }
        }
    }
}

// ---------------------------------------------------------------------------
// In-place RMSNorm on bf16 rows
// ---------------------------------------------------------------------------
__global__ __launch_bounds__(256) void rmsnorm_ip_k(
    u16* __restrict__ buf, const float* __restrict__ w, int cols, int stride)
{
    const int row = blockIdx.x;
    u16* xr = buf + (size_t)row * stride;
    float ss = 0.f;
    for (int c = threadIdx.x; c < cols; c += 256) { float v = b2f(xr[c]); ss += v * v; }
#pragma unroll
    for (int off = 32; off; off >>= 1) ss += __shfl_xor(ss, off);
    __shared__ float red[4];
    if ((threadIdx.x & 63) == 0) red[threadIdx.x >> 6] = ss;
    __syncthreads();
    const float tot = red[0] + red[1] + red[2] + red[3];
    const float inv = rsqrtf(tot / (float)cols + 1.1920929e-7f);
    for (int c = threadIdx.x; c < cols; c += 256)
        xr[c] = f2b(b2f(xr[c]) * inv * w[c]);
}

// ---------------------------------------------------------------------------
// RoPE kernels
// ---------------------------------------------------------------------------
__global__ __launch_bounds__(256) void rope_q_k(
    u16* __restrict__ qb, const float* __restrict__ fc, const float* __restrict__ fs)
{
    const int idx = blockIdx.x * 256 + threadIdx.x;
    const int i = idx & 31;
    const int h = (idx >> 5) & 15;
    const int row = idx >> 9;
    const int s = row & (SEQ - 1);
    ushort2* p = (ushort2*)(qb + (size_t)row * 3072 + h * 192 + 128) + i;
    ushort2 v = *p;
    const float xr = b2f(v.x), xi = b2f(v.y);
    const float c = fc[s * 32 + i], sn = fs[s * 32 + i];
    ushort2 o;
    o.x = f2b(xr * c - xi * sn);
    o.y = f2b(xr * sn + xi * c);
    *p = o;
}

__global__ __launch_bounds__(256) void rope_k_k(
    const u16* __restrict__ kvb, const float* __restrict__ fc,
    const float* __restrict__ fs, u16* __restrict__ krope)
{
    const int idx = blockIdx.x * 256 + threadIdx.x;
    const int i = idx & 31;
    const int row = idx >> 5;
    const int s = row & (SEQ - 1);
    const u16* src = kvb + (size_t)row * 576 + 512 + 2 * i;
    const float xr = b2f(src[0]), xi = b2f(src[1]);
    const float c = fc[s * 32 + i], sn = fs[s * 32 + i];
    ushort2 o;
    o.x = f2b(xr * c - xi * sn);
    o.y = f2b(xr * sn + xi * c);
    *((ushort2*)(krope + (size_t)row * 64) + i) = o;
}

// ---------------------------------------------------------------------------
// MFMA flash attention. Block = (b,h,64-q-rows); 4 waves x 16 rows; 32-key tiles.
// v_t column XOR-swizzled: element (row,key) lives at col key ^ (((row>>3)&7)<<2)
// -> V-transpose writes land in distinct banks (was 8-way, 4.3e7 conflicts).
// ---------------------------------------------------------------------------
__global__ __launch_bounds__(256) void attn_k(
    const u16* __restrict__ Q, const u16* __restrict__ KNV,
    const u16* __restrict__ KR, u16* __restrict__ O)
{
    __shared__ u16 k_lds[32][200];
    __shared__ u16 v_t[128][36];
    __shared__ u16 p_lds[4][16][36];

    const int tid  = threadIdx.x;
    const int lane = tid & 63;
    const int w    = tid >> 6;
    const int lr   = lane & 15;
    const int lq   = lane >> 4;

    const int bid = blockIdx.x;
    const int qt  = 31 - (bid >> 5);
    const int bh  = bid & 31;
    const int h   = bh & 15;
    const int b   = bh >> 4;
    const int q0  = qt * 64;
    const int bS  = b * SEQ;

    s16x8 qf[6];
    {
        const u16* qp = Q + (size_t)(bS + q0 + w * 16 + lr) * 3072 + h * 192 + (lq << 2);
#pragma unroll
        for (int kc = 0; kc < 6; kc++)
            qf[kc] = comb(*(const s16x4*)(qp + kc * 32),
                          *(const s16x4*)(qp + kc * 32 + 16));
    }

    f32x4 o_acc[8];
#pragma unroll
    for (int d = 0; d < 8; d++) o_acc[d] = (f32x4){0.f, 0.f, 0.f, 0.f};
    float m[4] = { -1e30f, -1e30f, -1e30f, -1e30f };
    float l[4] = { 0.f, 0.f, 0.f, 0.f };
    const float scale = 0.07216878364870323f;  // 192^-0.5
    const int qmin_w = q0 + w * 16;

    for (int kt0 = 0; kt0 < q0 + 64; kt0 += 32) {
        __syncthreads();
        const size_t knv0 = (size_t)(bS + kt0) * 4096 + h * 256;
#pragma unroll
        for (int t = 0; t < 5; t++) {
            int idx = tid + t * 256;
            if (idx < 512) {                         // K_nope
                int key = idx >> 4, c8 = (idx & 15) * 8;
                s16x8 v = *(const s16x8*)(KNV + knv0 + (size_t)key * 4096 + c8);
                *(s16x8*)&k_lds[key][c8] = v;
            } else if (idx < 768) {                  // K_rope
                int j = idx - 512;
                int key = j >> 3, c8 = (j & 7) * 8;
                s16x8 v = *(const s16x8*)(KR + (size_t)(bS + kt0 + key) * 64 + c8);
                *(s16x8*)&k_lds[key][128 + c8] = v;
            } else {                                 // V^T, XOR-swizzled cols
                int j = idx - 768;
                int key = j >> 4, d0 = (j & 15) * 8;
                s16x8 v = *(const s16x8*)(KNV + knv0 + (size_t)key * 4096 + 128 + d0);
                const int xw = (j & 7) << 2;         // ((d0>>3)&7)<<2
#pragma unroll
                for (int e = 0; e < 8; e++) v_t[d0 + e][key ^ xw] = (u16)v[e];
            }
        }
        __syncthreads();

        // QK^T
        f32x4 sa[2] = { (f32x4){0.f,0.f,0.f,0.f}, (f32x4){0.f,0.f,0.f,0.f} };
#pragma unroll
        for (int kc = 0; kc < 6; kc++) {
            const int kb = kc * 32 + (lq << 2);
#pragma unroll
            for (int f = 0; f < 2; f++) {
                s16x8 kf = comb(*(const s16x4*)&k_lds[f * 16 + lr][kb],
                                *(const s16x4*)&k_lds[f * 16 + lr][kb + 16]);
                sa[f] = __builtin_amdgcn_mfma_f32_16x16x32_bf16(qf[kc], kf, sa[f], 0, 0, 0);
            }
        }

        // online softmax
        const bool need_mask = (kt0 + 31 > qmin_w);
        float p[2][4];
#pragma unroll
        for (int f = 0; f < 2; f++)
#pragma unroll
            for (int r = 0; r < 4; r++) {
                float s = sa[f][r] * scale;
                if (need_mask) {
                    int key = kt0 + f * 16 + lr;
                    int qr  = qmin_w + lq * 4 + r;
                    if (key > qr) s = -1e30f;
                }
                p[f][r] = s;
            }
        float nm[4], corr[4];
#pragma unroll
        for (int r = 0; r < 4; r++) {
            float tm = fmaxf(p[0][r], p[1][r]);
#pragma unroll
            for (int off = 8; off; off >>= 1) tm = fmaxf(tm, __shfl_xor(tm, off));
            nm[r] = fmaxf(m[r], tm);
            corr[r] = __expf(m[r] - nm[r]);
            m[r] = nm[r];
        }
#pragma unroll
        for (int f = 0; f < 2; f++)
#pragma unroll
            for (int r = 0; r < 4; r++)
                p[f][r] = __expf(p[f][r] - nm[r]);
#pragma unroll
        for (int r = 0; r < 4; r++) {
            float ps = p[0][r] + p[1][r];
#pragma unroll
            for (int off = 8; off; off >>= 1) ps += __shfl_xor(ps, off);
            l[r] = l[r] * corr[r] + ps;
        }
#pragma unroll
        for (int d = 0; d < 8; d++)
#pragma unroll
            for (int r = 0; r < 4; r++) o_acc[d][r] *= corr[r];

#pragma unroll
        for (int f = 0; f < 2; f++)
#pragma unroll
            for (int r = 0; r < 4; r++)
                p_lds[w][lq * 4 + r][f * 16 + lr] = f2b(p[f][r]);
        asm volatile("s_waitcnt lgkmcnt(0)" ::: "memory");

        // PV (v_t read with matching XOR; b64s stay aligned since xr%4==0)
        s16x8 pa = comb(*(const s16x4*)&p_lds[w][lr][lq << 2],
                        *(const s16x4*)&p_lds[w][lr][16 + (lq << 2)]);
#pragma unroll
        for (int d = 0; d < 8; d++) {
            const int row = d * 16 + lr;
            const int xr0 = ((row >> 3) & 7) << 2;
            s16x8 vf = comb(*(const s16x4*)&v_t[row][(lq << 2) ^ xr0],
                            *(const s16x4*)&v_t[row][(16 + (lq << 2)) ^ xr0]);
            o_acc[d] = __builtin_amdgcn_mfma_f32_16x16x32_bf16(pa, vf, o_acc[d], 0, 0, 0);
        }
    }

    float invl[4];
#pragma unroll
    for (int r = 0; r < 4; r++) invl[r] = 1.f / l[r];
#pragma unroll
    for (int r = 0; r < 4; r++) {
        u16* op = O + (size_t)(bS + q0 + w * 16 + lq * 4 + r) * 2048 + h * 128 + lr;
#pragma unroll
        for (int d = 0; d < 8; d++)
            op[d * 16] = f2b(o_acc[d][r] * invl[r]);
    }
}

// ---------------------------------------------------------------------------
extern "C" void kernel_launch(void* const* d_in, const int* in_sizes, int n_in,
                              void* d_out, int out_size, void* d_ws, size_t ws_size,
                              hipStream_t stream)
{
    const float* x    = (const float*)d_in[0];
    const float* fc   = (const float*)d_in[1];
    const float* fs   = (const float*)d_in[2];
    const float* Wqd  = (const float*)d_in[3];
    const float* bqd  = (const float*)d_in[4];
    const float* qnw  = (const float*)d_in[5];
    const float* Wqu  = (const float*)d_in[6];
    const float* bqu  = (const float*)d_in[7];
    const float* Wkvd = (const float*)d_in[8];
    const float* bkvd = (const float*)d_in[9];
    const float* kvnw = (const float*)d_in[10];
    const float* Wkvu = (const float*)d_in[11];
    const float* bkvu = (const float*)d_in[12];
    const float* Wo   = (const float*)d_in[13];
    const float* bo   = (const float*)d_in[14];

    char* ws = (char*)d_ws;
    // Persistent activations (verified 76.5MB budget):
    u16* kvb     = (u16*)(ws);                 // [4096][576]
    u16* qlat    = (u16*)(ws + 4718592);       // [4096][1536] (dead after q-up)
    u16* qbuf    = (u16*)(ws + 17301504);      // [4096][3072]
    u16* krope   = (u16*)(ws + 42467328);      // [4096][64]
    u16* knv     = (u16*)(ws + 42991616);      // [4096][4096] (ends 76546048)
    u16* attn_o  = (u16*)(ws);                 // [4096][2048] reuses kvb+qlat
    // Transient bf16 copies, aliased into dead regions:
    u16* x_bf    = (u16*)(ws + 17301504);      // in qbuf slot (dead before q-up)
    u16* wqd_bf  = (u16*)(ws + 42991616);      // in knv slot (dead before kv-up)
    u16* wkvd_bf = (u16*)(ws + 49283072);      //   "
    u16* wqu_bf  = (u16*)(ws + 51642368);      //   "
    u16* wkvu_bf = (u16*)(ws + 4718592);       // in qlat slot (qlat dead by then)
    u16* wo_bf   = (u16*)(ws + 42991616);      // in knv slot (knv dead after attn)

    const int M = BATCH * SEQ;  // 4096

    // converts (f32 -> bf16)
    cvt_bf16_k<<<1024, 256, 0, stream>>>(x,    x_bf,    8388608 / 4);
    cvt_bf16_k<<<1024, 256, 0, stream>>>(Wqd,  wqd_bf,  3145728 / 4);
    cvt_bf16_k<<<1024, 256, 0, stream>>>(Wkvd, wkvd_bf, 1179648 / 4);
    cvt_bf16_k<<<1024, 256, 0, stream>>>(Wqu,  wqu_bf,  4718592 / 4);

    gemm_bf_k<1><<<dim3(12, 32), 256, 0, stream>>>(x_bf, wqd_bf, bqd, qlat, M, 1536, 2048, 2048);
    gemm_bf_k<1><<<dim3(5, 32),  256, 0, stream>>>(x_bf, wkvd_bf, bkvd, kvb, M, 576, 2048, 2048);
    rmsnorm_ip_k<<<M, 256, 0, stream>>>(qlat, qnw, 1536, 1536);
    rmsnorm_ip_k<<<M, 256, 0, stream>>>(kvb, kvnw, 512, 576);
    rope_k_k<<<(M * 32) / 256, 256, 0, stream>>>(kvb, fc, fs, krope);
    gemm_bf_k<1><<<dim3(24, 32), 256, 0, stream>>>(qlat, wqu_bf, bqu, qbuf, M, 3072, 1536, 1536);
    rope_q_k<<<(M * 16 * 32) / 256, 256, 0, stream>>>(qbuf, fc, fs);
    cvt_bf16_k<<<1024, 256, 0, stream>>>(Wkvu, wkvu_bf, 2097152 / 4);
    gemm_bf_k<1><<<dim3(32, 32), 256, 0, stream>>>(kvb, wkvu_bf, bkvu, knv, M, 4096, 512, 576);
    attn_k<<<BATCH * NHEAD * (SEQ / 64), 256, 0, stream>>>(qbuf, knv, krope, attn_o);
    cvt_bf16_k<<<1024, 256, 0, stream>>>(Wo, wo_bf, 4194304 / 4);
    gemm_bf_k<0><<<dim3(16, 32), 256, 0, stream>>>(attn_o, wo_bf, bo, (float*)d_out, M, 2048, 2048, 2048);
}

// Round 13
// 487.241 us; speedup vs baseline: 8.5382x; 1.0643x over previous
//
#include <hip/hip_runtime.h>

typedef unsigned short u16;
typedef short s16x8 __attribute__((ext_vector_type(8)));
typedef short s16x4 __attribute__((ext_vector_type(4)));
typedef float f32x4 __attribute__((ext_vector_type(4)));

#define SEQ   2048
#define BATCH 2
#define NHEAD 16

__device__ __forceinline__ float b2f(u16 u) {
    unsigned x = ((unsigned)u) << 16;
    return __builtin_bit_cast(float, x);
}
__device__ __forceinline__ u16 f2b(float f) {
    unsigned x = __builtin_bit_cast(unsigned, f);
    unsigned r = (x + 0x7fffu + ((x >> 16) & 1u)) >> 16;
    return (u16)r;
}
__device__ __forceinline__ s16x8 comb(s16x4 lo, s16x4 hi) {
    return __builtin_shufflevector(lo, hi, 0, 1, 2, 3, 4, 5, 6, 7);
}
__device__ __forceinline__ void gload16(const void* g, void* l) {
    __builtin_amdgcn_global_load_lds(
        (const __attribute__((address_space(1))) void*)g,
        (__attribute__((address_space(3))) void*)l, 16, 0, 0);
}

// ---------------------------------------------------------------------------
// f32 -> bf16 convert (vectorized, grid-stride). n % 4 == 0.
// ---------------------------------------------------------------------------
__global__ __launch_bounds__(256) void cvt_bf16_k(
    const float* __restrict__ in, u16* __restrict__ out, int n4)
{
    int i = blockIdx.x * 256 + threadIdx.x;
    const int stride = gridDim.x * 256;
    for (; i < n4; i += stride) {
        float4 v = ((const float4*)in)[i];
        ushort4 o = { f2b(v.x), f2b(v.y), f2b(v.z), f2b(v.w) };
        ((ushort4*)out)[i] = o;
    }
}

// ---------------------------------------------------------------------------
// m97-style MFMA GEMM: C[M,N] = A[M,K](bf16) @ W[N,K](bf16)^T + bias[N](f32)
// ---------------------------------------------------------------------------
template <int OUT_BF16>
__global__ __launch_bounds__(256) void gemm_bf_k(
    const u16* __restrict__ A, const u16* __restrict__ W,
    const float* __restrict__ bias, void* __restrict__ Cout,
    int M, int N, int K, int lda)
{
    __shared__ u16 lsA[128 * 64];
    __shared__ u16 lsB[128 * 64];
    const int tid  = threadIdx.x;
    const int lane = tid & 63;
    const int w    = tid >> 6;
    const int wm   = w >> 1, wn = w & 1;
    const int row0 = blockIdx.y * 128;
    const int col0 = blockIdx.x * 128;
    const int lr8  = lane >> 3;
    const int lc8  = (lane & 7) * 8;

    f32x4 acc[4][4];
#pragma unroll
    for (int i = 0; i < 4; i++)
#pragma unroll
        for (int j = 0; j < 4; j++) acc[i][j] = (f32x4){0.f, 0.f, 0.f, 0.f};

    for (int kt = 0; kt < K; kt += 64) {
#pragma unroll
        for (int t = 0; t < 4; t++) {
            const int r = w * 32 + t * 8;
            gload16(A + (size_t)(row0 + r + lr8) * lda + kt + lc8, &lsA[r * 64]);
            int rw = col0 + r + lr8; if (rw >= N) rw = N - 1;
            gload16(W + (size_t)rw * K + kt + lc8, &lsB[r * 64]);
        }
        __syncthreads();
#pragma unroll
        for (int ks = 0; ks < 2; ks++) {
            const int ko = ks * 32 + (lane >> 4) * 8;
            s16x8 af[4], bfr[4];
#pragma unroll
            for (int i = 0; i < 4; i++) {
                af[i]  = *(const s16x8*)&lsA[(wm * 64 + i * 16 + (lane & 15)) * 64 + ko];
                bfr[i] = *(const s16x8*)&lsB[(wn * 64 + i * 16 + (lane & 15)) * 64 + ko];
            }
#pragma unroll
            for (int mf = 0; mf < 4; mf++)
#pragma unroll
                for (int nf = 0; nf < 4; nf++)
                    acc[mf][nf] = __builtin_amdgcn_mfma_f32_16x16x32_bf16(
                        af[mf], bfr[nf], acc[mf][nf], 0, 0, 0);
        }
        __syncthreads();
    }

    const int rb = row0 + wm * 64 + ((lane >> 4) << 2);
    const int cb = col0 + wn * 64 + (lane & 15);
#pragma unroll
    for (int nf = 0; nf < 4; nf++) {
        const int col = cb + nf * 16;
        if (col < N) {
            const float bv = bias[col];
#pragma unroll
            for (int mf = 0; mf < 4; mf++)
#pragma unroll
                for (int r = 0; r < 4; r++) {
                    const int row = rb + mf * 16 + r;
                    float v = acc[mf][nf][r] + bv;
                    if (OUT_BF16) ((u16*)Cout)[(size_t)row * N + col] = f2b(v);
                    else          ((float*)Cout)[(size_t)row * N + col] = v;
                }
        }
    }
}

// ---------------------------------------------------------------------------
// In-place RMSNorm on bf16 rows
// ---------------------------------------------------------------------------
__global__ __launch_bounds__(256) void rmsnorm_ip_k(
    u16* __restrict__ buf, const float* __restrict__ w, int cols, int stride)
{
    const int row = blockIdx.x;
    u16* xr = buf + (size_t)row * stride;
    float ss = 0.f;
    for (int c = threadIdx.x; c < cols; c += 256) { float v = b2f(xr[c]); ss += v * v; }
#pragma unroll
    for (int off = 32; off; off >>= 1) ss += __shfl_xor(ss, off);
    __shared__ float red[4];
    if ((threadIdx.x & 63) == 0) red[threadIdx.x >> 6] = ss;
    __syncthreads();
    const float tot = red[0] + red[1] + red[2] + red[3];
    const float inv = rsqrtf(tot / (float)cols + 1.1920929e-7f);
    for (int c = threadIdx.x; c < cols; c += 256)
        xr[c] = f2b(b2f(xr[c]) * inv * w[c]);
}

// ---------------------------------------------------------------------------
// RoPE kernels
// ---------------------------------------------------------------------------
__global__ __launch_bounds__(256) void rope_q_k(
    u16* __restrict__ qb, const float* __restrict__ fc, const float* __restrict__ fs)
{
    const int idx = blockIdx.x * 256 + threadIdx.x;
    const int i = idx & 31;
    const int h = (idx >> 5) & 15;
    const int row = idx >> 9;
    const int s = row & (SEQ - 1);
    ushort2* p = (ushort2*)(qb + (size_t)row * 3072 + h * 192 + 128) + i;
    ushort2 v = *p;
    const float xr = b2f(v.x), xi = b2f(v.y);
    const float c = fc[s * 32 + i], sn = fs[s * 32 + i];
    ushort2 o;
    o.x = f2b(xr * c - xi * sn);
    o.y = f2b(xr * sn + xi * c);
    *p = o;
}

__global__ __launch_bounds__(256) void rope_k_k(
    const u16* __restrict__ kvb, const float* __restrict__ fc,
    const float* __restrict__ fs, u16* __restrict__ krope)
{
    const int idx = blockIdx.x * 256 + threadIdx.x;
    const int i = idx & 31;
    const int row = idx >> 5;
    const int s = row & (SEQ - 1);
    const u16* src = kvb + (size_t)row * 576 + 512 + 2 * i;
    const float xr = b2f(src[0]), xi = b2f(src[1]);
    const float c = fc[s * 32 + i], sn = fs[s * 32 + i];
    ushort2 o;
    o.x = f2b(xr * c - xi * sn);
    o.y = f2b(xr * sn + xi * c);
    *((ushort2*)(krope + (size_t)row * 64) + i) = o;
}

// ---------------------------------------------------------------------------
// MFMA flash attention v3.
// Block = (b,h,128 q-rows); 4 waves x 32 rows (2 m-frags); KVBLK=64.
// Register prefetch of next K/V tile overlaps compute (T14 pattern).
// v_t swizzle: element (row,key) stored at col key ^ ((row>>4)<<2) -> 2-way
// writes (free); read XOR is constant per instruction, 4-aligned.
// ---------------------------------------------------------------------------
__global__ __launch_bounds__(256, 2) void attn_k(
    const u16* __restrict__ Q, const u16* __restrict__ KNV,
    const u16* __restrict__ KR, u16* __restrict__ O)
{
    __shared__ u16 k_lds[64][200];    // 64 keys x 192 dims
    __shared__ u16 v_t[128][68];      // V^T swizzled: [dim][key]
    __shared__ u16 p_lds[4][32][68];  // per-wave P: [qrow][key]

    const int tid  = threadIdx.x;
    const int lane = tid & 63;
    const int w    = tid >> 6;
    const int lr   = lane & 15;
    const int lq   = lane >> 4;

    const int bid = blockIdx.x;
    const int qt  = 15 - (bid >> 5);       // heavy tiles first
    const int bh  = bid & 31;
    const int h   = bh & 15;
    const int b   = bh >> 4;
    const int q0  = qt * 128;
    const int bS  = b * SEQ;

    // Q fragments: 2 m-blocks x 6 k-chunks, rows q0 + w*32 + mb*16 + lr
    s16x8 qf[2][6];
#pragma unroll
    for (int mb = 0; mb < 2; mb++) {
        const u16* qp = Q + (size_t)(bS + q0 + w * 32 + mb * 16 + lr) * 3072
                        + h * 192 + (lq << 2);
#pragma unroll
        for (int kc = 0; kc < 6; kc++)
            qf[mb][kc] = comb(*(const s16x4*)(qp + kc * 32),
                              *(const s16x4*)(qp + kc * 32 + 16));
    }

    f32x4 o_acc[2][8];
#pragma unroll
    for (int mb = 0; mb < 2; mb++)
#pragma unroll
        for (int d = 0; d < 8; d++) o_acc[mb][d] = (f32x4){0.f, 0.f, 0.f, 0.f};
    float m[2][4], l[2][4];
#pragma unroll
    for (int mb = 0; mb < 2; mb++)
#pragma unroll
        for (int r = 0; r < 4; r++) { m[mb][r] = -1e30f; l[mb][r] = 0.f; }

    const float scale = 0.07216878364870323f;  // 192^-0.5
    const int ntiles = (q0 + 128) / 64;

    // staging registers (prefetch): K 6 chunks, V 4 chunks per thread
    s16x8 kr[6], vr[4];
    const int kkey = tid >> 2;             // K: 4 threads/key, 48 cols each
    const int ka   = tid & 3;

    // ---- load tile 0 -------------------------------------------------------
    {
        const u16* kn  = KNV + (size_t)(bS + kkey) * 4096 + h * 256;
        const u16* krp = KR + (size_t)(bS + kkey) * 64;
#pragma unroll
        for (int i = 0; i < 6; i++) {
            const int col = ka * 48 + i * 8;
            kr[i] = *(const s16x8*)(col < 128 ? kn + col : krp + (col - 128));
        }
#pragma unroll
        for (int i = 0; i < 4; i++) {
            const int idx = tid + i * 256;
            vr[i] = *(const s16x8*)(KNV + (size_t)(bS + (idx >> 4)) * 4096
                                    + h * 256 + 128 + (idx & 15) * 8);
        }
    }

    for (int t = 0; t < ntiles; t++) {
        // ---- store staged tile to LDS -------------------------------------
#pragma unroll
        for (int i = 0; i < 6; i++)
            *(s16x8*)&k_lds[kkey][ka * 48 + i * 8] = kr[i];
#pragma unroll
        for (int i = 0; i < 4; i++) {
            const int idx = tid + i * 256;
            const int key = idx >> 4, d0 = (idx & 15) * 8;
            const int xw = (d0 >> 4) << 2;     // (row>>4)<<2, const over e<8
#pragma unroll
            for (int e = 0; e < 8; e++) v_t[d0 + e][key ^ xw] = (u16)vr[i][e];
        }
        __syncthreads();

        // ---- issue prefetch for next tile (overlaps compute) --------------
        if (t + 1 < ntiles) {
            const int nk = (t + 1) * 64;
            const u16* kn  = KNV + (size_t)(bS + nk + kkey) * 4096 + h * 256;
            const u16* krp = KR + (size_t)(bS + nk + kkey) * 64;
#pragma unroll
            for (int i = 0; i < 6; i++) {
                const int col = ka * 48 + i * 8;
                kr[i] = *(const s16x8*)(col < 128 ? kn + col : krp + (col - 128));
            }
#pragma unroll
            for (int i = 0; i < 4; i++) {
                const int idx = tid + i * 256;
                vr[i] = *(const s16x8*)(KNV + (size_t)(bS + nk + (idx >> 4)) * 4096
                                        + h * 256 + 128 + (idx & 15) * 8);
            }
        }

        const int kt0 = t * 64;

        // ---- QK^T: 4 key-frags x 6 k-chunks x 2 m-blocks ------------------
        f32x4 sa[2][4];
#pragma unroll
        for (int mb = 0; mb < 2; mb++)
#pragma unroll
            for (int f = 0; f < 4; f++) sa[mb][f] = (f32x4){0.f, 0.f, 0.f, 0.f};
#pragma unroll
        for (int kc = 0; kc < 6; kc++) {
            const int kb = kc * 32 + (lq << 2);
#pragma unroll
            for (int f = 0; f < 4; f++) {
                s16x8 kf = comb(*(const s16x4*)&k_lds[f * 16 + lr][kb],
                                *(const s16x4*)&k_lds[f * 16 + lr][kb + 16]);
                sa[0][f] = __builtin_amdgcn_mfma_f32_16x16x32_bf16(qf[0][kc], kf, sa[0][f], 0, 0, 0);
                sa[1][f] = __builtin_amdgcn_mfma_f32_16x16x32_bf16(qf[1][kc], kf, sa[1][f], 0, 0, 0);
            }
        }

        // ---- online softmax per m-block -----------------------------------
#pragma unroll
        for (int mb = 0; mb < 2; mb++) {
            const int qbase = q0 + w * 32 + mb * 16 + lq * 4;
            const bool need_mask = (kt0 + 63 > qbase);
            float p[4][4];
#pragma unroll
            for (int f = 0; f < 4; f++)
#pragma unroll
                for (int r = 0; r < 4; r++) {
                    float s = sa[mb][f][r] * scale;
                    if (need_mask && (kt0 + f * 16 + lr > qbase + r)) s = -1e30f;
                    p[f][r] = s;
                }
            float nm[4], corr[4];
#pragma unroll
            for (int r = 0; r < 4; r++) {
                float tm = fmaxf(fmaxf(p[0][r], p[1][r]), fmaxf(p[2][r], p[3][r]));
#pragma unroll
                for (int off = 8; off; off >>= 1) tm = fmaxf(tm, __shfl_xor(tm, off));
                nm[r] = fmaxf(m[mb][r], tm);
                corr[r] = __expf(m[mb][r] - nm[r]);
                m[mb][r] = nm[r];
            }
#pragma unroll
            for (int f = 0; f < 4; f++)
#pragma unroll
                for (int r = 0; r < 4; r++)
                    p[f][r] = __expf(p[f][r] - nm[r]);
#pragma unroll
            for (int r = 0; r < 4; r++) {
                float ps = (p[0][r] + p[1][r]) + (p[2][r] + p[3][r]);
#pragma unroll
                for (int off = 8; off; off >>= 1) ps += __shfl_xor(ps, off);
                l[mb][r] = l[mb][r] * corr[r] + ps;
            }
#pragma unroll
            for (int d = 0; d < 8; d++)
#pragma unroll
                for (int r = 0; r < 4; r++) o_acc[mb][d][r] *= corr[r];
#pragma unroll
            for (int f = 0; f < 4; f++)
#pragma unroll
                for (int r = 0; r < 4; r++)
                    p_lds[w][mb * 16 + lq * 4 + r][f * 16 + lr] = f2b(p[f][r]);
        }
        asm volatile("s_waitcnt lgkmcnt(0)" ::: "memory");

        // ---- PV: 2 k-halves x 8 d-frags x 2 m-blocks ----------------------
#pragma unroll
        for (int hf = 0; hf < 2; hf++) {
            const int pc = hf * 32 + (lq << 2);
            s16x8 pa0 = comb(*(const s16x4*)&p_lds[w][lr][pc],
                             *(const s16x4*)&p_lds[w][lr][pc + 16]);
            s16x8 pa1 = comb(*(const s16x4*)&p_lds[w][16 + lr][pc],
                             *(const s16x4*)&p_lds[w][16 + lr][pc + 16]);
#pragma unroll
            for (int d = 0; d < 8; d++) {
                const int row = d * 16 + lr;
                const int xr0 = d << 2;        // (row>>4)<<2
                s16x8 vf = comb(*(const s16x4*)&v_t[row][pc ^ xr0],
                                *(const s16x4*)&v_t[row][(pc + 16) ^ xr0]);
                o_acc[0][d] = __builtin_amdgcn_mfma_f32_16x16x32_bf16(pa0, vf, o_acc[0][d], 0, 0, 0);
                o_acc[1][d] = __builtin_amdgcn_mfma_f32_16x16x32_bf16(pa1, vf, o_acc[1][d], 0, 0, 0);
            }
        }
        __syncthreads();
    }

    // ---- epilogue ---------------------------------------------------------
#pragma unroll
    for (int mb = 0; mb < 2; mb++) {
        float invl[4];
#pragma unroll
        for (int r = 0; r < 4; r++) invl[r] = 1.f / l[mb][r];
#pragma unroll
        for (int r = 0; r < 4; r++) {
            u16* op = O + (size_t)(bS + q0 + w * 32 + mb * 16 + lq * 4 + r) * 2048
                      + h * 128 + lr;
#pragma unroll
            for (int d = 0; d < 8; d++)
                op[d * 16] = f2b(o_acc[mb][d][r] * invl[r]);
        }
    }
}

// ---------------------------------------------------------------------------
extern "C" void kernel_launch(void* const* d_in, const int* in_sizes, int n_in,
                              void* d_out, int out_size, void* d_ws, size_t ws_size,
                              hipStream_t stream)
{
    const float* x    = (const float*)d_in[0];
    const float* fc   = (const float*)d_in[1];
    const float* fs   = (const float*)d_in[2];
    const float* Wqd  = (const float*)d_in[3];
    const float* bqd  = (const float*)d_in[4];
    const float* qnw  = (const float*)d_in[5];
    const float* Wqu  = (const float*)d_in[6];
    const float* bqu  = (const float*)d_in[7];
    const float* Wkvd = (const float*)d_in[8];
    const float* bkvd = (const float*)d_in[9];
    const float* kvnw = (const float*)d_in[10];
    const float* Wkvu = (const float*)d_in[11];
    const float* bkvu = (const float*)d_in[12];
    const float* Wo   = (const float*)d_in[13];
    const float* bo   = (const float*)d_in[14];

    char* ws = (char*)d_ws;
    u16* kvb     = (u16*)(ws);                 // [4096][576]
    u16* qlat    = (u16*)(ws + 4718592);       // [4096][1536]
    u16* qbuf    = (u16*)(ws + 17301504);      // [4096][3072]
    u16* krope   = (u16*)(ws + 42467328);      // [4096][64]
    u16* knv     = (u16*)(ws + 42991616);      // [4096][4096]
    u16* attn_o  = (u16*)(ws);                 // [4096][2048] reuses kvb+qlat
    u16* x_bf    = (u16*)(ws + 17301504);      // in qbuf slot
    u16* wqd_bf  = (u16*)(ws + 42991616);      // in knv slot
    u16* wkvd_bf = (u16*)(ws + 49283072);
    u16* wqu_bf  = (u16*)(ws + 51642368);
    u16* wkvu_bf = (u16*)(ws + 4718592);       // in qlat slot
    u16* wo_bf   = (u16*)(ws + 42991616);      // in knv slot

    const int M = BATCH * SEQ;  // 4096

    cvt_bf16_k<<<1024, 256, 0, stream>>>(x,    x_bf,    8388608 / 4);
    cvt_bf16_k<<<1024, 256, 0, stream>>>(Wqd,  wqd_bf,  3145728 / 4);
    cvt_bf16_k<<<1024, 256, 0, stream>>>(Wkvd, wkvd_bf, 1179648 / 4);
    cvt_bf16_k<<<1024, 256, 0, stream>>>(Wqu,  wqu_bf,  4718592 / 4);

    gemm_bf_k<1><<<dim3(12, 32), 256, 0, stream>>>(x_bf, wqd_bf, bqd, qlat, M, 1536, 2048, 2048);
    gemm_bf_k<1><<<dim3(5, 32),  256, 0, stream>>>(x_bf, wkvd_bf, bkvd, kvb, M, 576, 2048, 2048);
    rmsnorm_ip_k<<<M, 256, 0, stream>>>(qlat, qnw, 1536, 1536);
    rmsnorm_ip_k<<<M, 256, 0, stream>>>(kvb, kvnw, 512, 576);
    rope_k_k<<<(M * 32) / 256, 256, 0, stream>>>(kvb, fc, fs, krope);
    gemm_bf_k<1><<<dim3(24, 32), 256, 0, stream>>>(qlat, wqu_bf, bqu, qbuf, M, 3072, 1536, 1536);
    rope_q_k<<<(M * 16 * 32) / 256, 256, 0, stream>>>(qbuf, fc, fs);
    cvt_bf16_k<<<1024, 256, 0, stream>>>(Wkvu, wkvu_bf, 2097152 / 4);
    gemm_bf_k<1><<<dim3(32, 32), 256, 0, stream>>>(kvb, wkvu_bf, bkvu, knv, M, 4096, 512, 576);
    attn_k<<<BATCH * NHEAD * (SEQ / 128), 256, 0, stream>>>(qbuf, knv, krope, attn_o);
    cvt_bf16_k<<<1024, 256, 0, stream>>>(Wo, wo_bf, 4194304 / 4);
    gemm_bf_k<0><<<dim3(16, 32), 256, 0, stream>>>(attn_o, wo_bf, bo, (float*)d_out, M, 2048, 2048, 2048);
}